// Round 7
// baseline (502.381 us; speedup 1.0000x reference)
//
#include <hip/hip_runtime.h>

// Problem constants (fixed-shape problem)
constexpr int N_    = 8;
constexpr int M_    = 50000;
constexpr int FIN_  = 16;
constexpr int FOUT_ = 32;
constexpr int KCH_  = 4;
constexpr int NNZ_  = 800000;
constexpr int ROW_  = FIN_ * N_;   // 128 floats per term row
constexpr int SCAN_NB = (M_ + 255) / 256;   // 196 scan blocks
constexpr int MT_   = 2;                    // m-values per thread in k_final
constexpr int MTILES_ = M_ / MT_;           // 25000 m-tiles (exact)
constexpr int NSLICE_ = 8;                  // term-buffer slices (one per XCD)
constexpr int SW_     = ROW_ / NSLICE_;     // 16 floats per slice
constexpr int RPB_    = 64;                 // rows per spmm block (256 thr / 4 lanes)
constexpr int RBLK_   = (M_ + RPB_ - 1) / RPB_;   // 782 row-blocks per slice

// native vector type for nontemporal builtins (HIP float4 is a class type,
// which __builtin_nontemporal_* rejects)
typedef float f32x4 __attribute__((ext_vector_type(4)));

// Term-buffer layout: T[(s*M + m)*16 + w]  where  s*16+w == f*8+n
// => per-XCD slice footprint 3.2 MB (fits 4 MB private L2)

// ---------------------------------------------------------------------------
// X0 in slice layout: thread per destination element (coalesced write)
__global__ void k_build_x0(const float* __restrict__ x, float* __restrict__ t0) {
    int t = blockIdx.x * blockDim.x + threadIdx.x;
    if (t >= M_ * ROW_) return;
    int w = t & 15;
    int m = (t >> 4) % M_;
    int s = t / (M_ * 16);
    int idx = s * 16 + w;           // = f*8 + n
    int f = idx >> 3;
    int n = idx & 7;
    t0[t] = x[((size_t)n * M_ + m) * FIN_ + f];
}

// row histogram
__global__ void k_hist(const int* __restrict__ row, int* __restrict__ cnt) {
    int i = blockIdx.x * blockDim.x + threadIdx.x;
    if (i < NNZ_) atomicAdd(&cnt[row[i]], 1);
}

// per-block sums of cnt (256 elems per block)
__global__ void k_blocksum(const int* __restrict__ cnt, int* __restrict__ bsum) {
    __shared__ int s[256];
    int t = threadIdx.x;
    int idx = blockIdx.x * 256 + t;
    s[t] = (idx < M_) ? cnt[idx] : 0;
    __syncthreads();
    for (int off = 128; off > 0; off >>= 1) {
        if (t < off) s[t] += s[t + off];
        __syncthreads();
    }
    if (t == 0) bsum[blockIdx.x] = s[0];
}

// single-block exclusive scan of bsum[SCAN_NB] -> boff[SCAN_NB]
__global__ void k_scan_bsum(const int* __restrict__ bsum, int* __restrict__ boff) {
    __shared__ int s[256];
    int t = threadIdx.x;
    int v = (t < SCAN_NB) ? bsum[t] : 0;
    s[t] = v;
    __syncthreads();
    for (int off = 1; off < 256; off <<= 1) {
        int a = (t >= off) ? s[t - off] : 0;
        __syncthreads();
        s[t] += a;
        __syncthreads();
    }
    if (t < SCAN_NB) boff[t] = s[t] - v;   // exclusive
}

// per-block local exclusive scan + global offset -> row_ptr, row_tmp
__global__ void k_emit(const int* __restrict__ cnt, const int* __restrict__ boff,
                       int* __restrict__ row_ptr, int* __restrict__ row_tmp) {
    __shared__ int s[256];
    int t = threadIdx.x;
    int idx = blockIdx.x * 256 + t;
    int v = (idx < M_) ? cnt[idx] : 0;
    s[t] = v;
    __syncthreads();
    for (int off = 1; off < 256; off <<= 1) {
        int a = (t >= off) ? s[t - off] : 0;
        __syncthreads();
        s[t] += a;
        __syncthreads();
    }
    if (idx < M_) {
        int r = boff[blockIdx.x] + s[t] - v;   // exclusive global offset
        row_ptr[idx] = r;
        row_tmp[idx] = r;
    }
    if (idx == 0) row_ptr[M_] = NNZ_;
}

// scatter nnz into CSR order, packing (val, col) into int2
__global__ void k_scatter(const float* __restrict__ vals, const int* __restrict__ row,
                          const int* __restrict__ col, int* __restrict__ row_tmp,
                          int2* __restrict__ pairs) {
    int i = blockIdx.x * blockDim.x + threadIdx.x;
    if (i >= NNZ_) return;
    int p = atomicAdd(&row_tmp[row[i]], 1);
    pairs[p] = make_int2(__float_as_int(vals[i]), col[i]);
}

// Slice-local SpMM: Y[s,r,:] = scale * sum_j v_j * X[s,c_j,:] (- prev[s,r,:])
// blockIdx&7 = slice -> one slice per XCD (round-robin dispatch heuristic).
// 4 lanes per row: pairs load broadcast in quad, 16 B gather per lane.
__global__ __launch_bounds__(256) void k_spmm_slice(
        const float* __restrict__ X, const float* __restrict__ prev,
        float* __restrict__ Y, const int* __restrict__ rp,
        const int2* __restrict__ pairs, float scale) {
    const int s  = blockIdx.x & 7;
    const int rb = blockIdx.x >> 3;
    const int r  = rb * RPB_ + (threadIdx.x >> 2);
    if (r >= M_) return;
    const int w4 = (threadIdx.x & 3) * 4;

    const float* Xs = X + (size_t)s * M_ * SW_;
    const size_t off = ((size_t)s * M_ + r) * SW_ + w4;

    f32x4 acc;
    if (prev) {
        f32x4 p = __builtin_nontemporal_load(
            reinterpret_cast<const f32x4*>(prev + off));
        acc = -p;
    } else {
        acc = (f32x4)0.f;
    }

    const long long* pr = reinterpret_cast<const long long*>(pairs);
    int jb = rp[r], je = rp[r + 1];
#pragma unroll 2
    for (int j = jb; j < je; ++j) {
        long long pc = __builtin_nontemporal_load(pr + j);
        float v = scale * __int_as_float((int)(pc & 0xffffffffLL));
        int   c = (int)(pc >> 32);
        f32x4 xv = *reinterpret_cast<const f32x4*>(Xs + (size_t)c * SW_ + w4);
        acc += v * xv;
    }
    __builtin_nontemporal_store(acc, reinterpret_cast<f32x4*>(Y + off));
}

// fused final einsum over all 4 terms (slice-layout reads).
// Thread = (n, 2 consecutive m), all 32 o in registers.
// For fixed f: slice s = f>>1, w = n + 8*(f&1)  (compile-time per f).
__global__ __launch_bounds__(256, 4) void k_final(
        const float* __restrict__ T0, const float* __restrict__ T1,
        const float* __restrict__ T2, const float* __restrict__ T3,
        const float* __restrict__ w, const float* __restrict__ b,
        float* __restrict__ out) {
    int t = blockIdx.x * blockDim.x + threadIdx.x;
    if (t >= MTILES_ * N_) return;
    const int n  = t & 7;
    const int m0 = (t >> 3) * MT_;

    float4 acc[MT_][8];
#pragma unroll
    for (int o4 = 0; o4 < 8; ++o4) {
        float4 bv = *reinterpret_cast<const float4*>(b + o4 * 4);   // uniform
#pragma unroll
        for (int i = 0; i < MT_; ++i) acc[i][o4] = bv;
    }

    const float* Ts[4] = {T0, T1, T2, T3};
#pragma unroll
    for (int k = 0; k < KCH_; ++k) {
        const float* tb = Ts[k] + (size_t)m0 * SW_ + n;
#pragma unroll
        for (int f = 0; f < FIN_; ++f) {
            const size_t foff = (size_t)(f >> 1) * M_ * SW_ + 8 * (f & 1);
            float tv0 = tb[foff];
            float tv1 = tb[foff + SW_];
            const float* wr = w + (f * KCH_ + k) * FOUT_;   // uniform
#pragma unroll
            for (int o4 = 0; o4 < 8; ++o4) {
                float4 wv = *reinterpret_cast<const float4*>(wr + o4 * 4);
                acc[0][o4].x += tv0 * wv.x;
                acc[0][o4].y += tv0 * wv.y;
                acc[0][o4].z += tv0 * wv.z;
                acc[0][o4].w += tv0 * wv.w;
                acc[1][o4].x += tv1 * wv.x;
                acc[1][o4].y += tv1 * wv.y;
                acc[1][o4].z += tv1 * wv.z;
                acc[1][o4].w += tv1 * wv.w;
            }
        }
    }

#pragma unroll
    for (int i = 0; i < MT_; ++i) {
        float* base = out + ((size_t)n * M_ + (m0 + i)) * FOUT_;
#pragma unroll
        for (int o4 = 0; o4 < 8; ++o4)
            *reinterpret_cast<float4*>(base + o4 * 4) = acc[i][o4];
    }
}

// per-term accumulation (fallback path, small ws), slice-layout reads
__global__ void k_accum(const float* __restrict__ T, const float* __restrict__ w,
                        const float* __restrict__ b, float* __restrict__ out,
                        int k, int init) {
    int t = blockIdx.x * blockDim.x + threadIdx.x;
    if (t >= M_ * FOUT_) return;
    int o = t & 31;
    int m = t >> 5;
    float acc[8];
    if (init) {
        float bias = b[o];
#pragma unroll
        for (int n = 0; n < 8; ++n) acc[n] = bias;
    } else {
#pragma unroll
        for (int n = 0; n < 8; ++n) acc[n] = out[((size_t)n * M_ + m) * FOUT_ + o];
    }
#pragma unroll
    for (int f = 0; f < FIN_; ++f) {
        float wk = w[(f * KCH_ + k) * FOUT_ + o];
        const float* tr = T + (size_t)(f >> 1) * M_ * SW_ + (size_t)m * SW_ + 8 * (f & 1);
#pragma unroll
        for (int n = 0; n < 8; ++n)
            acc[n] += tr[n] * wk;
    }
#pragma unroll
    for (int n = 0; n < 8; ++n)
        out[((size_t)n * M_ + m) * FOUT_ + o] = acc[n];
}

// ---------------------------------------------------------------------------
extern "C" void kernel_launch(void* const* d_in, const int* in_sizes, int n_in,
                              void* d_out, int out_size, void* d_ws, size_t ws_size,
                              hipStream_t stream) {
    const float* x    = (const float*)d_in[0];
    const float* vals = (const float*)d_in[1];
    const float* w    = (const float*)d_in[2];
    const float* b    = (const float*)d_in[3];
    const int*   row  = (const int*)d_in[4];
    const int*   col  = (const int*)d_in[5];
    float* out = (float*)d_out;

    const size_t tElems = (size_t)M_ * ROW_;             // 6.4M floats per term
    const size_t csrBytes = (size_t)(M_ + 1) * 4 + (size_t)M_ * 4
                          + (size_t)NNZ_ * 8 + 2048;
    const size_t fusedBytes = 4 * tElems * 4 + csrBytes; // ~109 MB
    const bool fused = ws_size >= fusedBytes;

    float* T0 = (float*)d_ws;
    float* T1 = T0 + tElems;
    float* T2 = fused ? (T1 + tElems) : nullptr;
    float* T3 = fused ? (T2 + tElems) : nullptr;
    char*  p  = (char*)(fused ? (T3 + tElems) : (T1 + tElems));
    int*   row_ptr = (int*)p;              p += (size_t)(M_ + 1) * 4;
    int*   row_tmp = (int*)p;              p += (size_t)M_ * 4;
    int2*  pairs   = (int2*)p;             p += (size_t)NNZ_ * 8;
    int*   bsum    = (int*)p;              p += 1024;
    int*   boff    = (int*)p;

    const int TB = 256;
    dim3 blk(TB);
    dim3 gT(((int)tElems + TB - 1) / TB);          // term-sized elementwise
    dim3 gN((NNZ_ + TB - 1) / TB);                 // per-nnz
    dim3 gS(RBLK_ * NSLICE_);                      // spmm: slice-interleaved
    dim3 gF2((MTILES_ * N_ + TB - 1) / TB);        // k_final threads
    dim3 gF((M_ * FOUT_ + TB - 1) / TB);           // fallback k_accum

    // ---- build CSR (per call) ----
    hipMemsetAsync(row_tmp, 0, (size_t)M_ * 4, stream);     // row_tmp doubles as cnt
    hipLaunchKernelGGL(k_hist,      gN, blk, 0, stream, row, row_tmp);
    hipLaunchKernelGGL(k_blocksum,  dim3(SCAN_NB), blk, 0, stream, row_tmp, bsum);
    hipLaunchKernelGGL(k_scan_bsum, dim3(1), blk, 0, stream, bsum, boff);
    hipLaunchKernelGGL(k_emit,      dim3(SCAN_NB), blk, 0, stream, row_tmp, boff,
                       row_ptr, row_tmp);
    hipLaunchKernelGGL(k_scatter,   gN, blk, 0, stream, vals, row, col, row_tmp, pairs);

    // ---- Chebyshev terms (slice layout) ----
    hipLaunchKernelGGL(k_build_x0, gT, blk, 0, stream, x, T0);
    hipLaunchKernelGGL(k_spmm_slice, gS, blk, 0, stream, T0, (const float*)nullptr, T1,
                       row_ptr, pairs, 1.0f);

    if (fused) {
        hipLaunchKernelGGL(k_spmm_slice, gS, blk, 0, stream, T1, T0, T2,
                           row_ptr, pairs, 2.0f);
        hipLaunchKernelGGL(k_spmm_slice, gS, blk, 0, stream, T2, T1, T3,
                           row_ptr, pairs, 2.0f);
        hipLaunchKernelGGL(k_final, gF2, blk, 0, stream, T0, T1, T2, T3, w, b, out);
    } else {
        hipLaunchKernelGGL(k_accum, gF, blk, 0, stream, T0, w, b, out, 0, 1);
        hipLaunchKernelGGL(k_accum, gF, blk, 0, stream, T1, w, b, out, 1, 0);
        hipLaunchKernelGGL(k_spmm_slice, gS, blk, 0, stream, T1, T0, T0,
                           row_ptr, pairs, 2.0f);        // T2 overwrites T0
        hipLaunchKernelGGL(k_accum, gF, blk, 0, stream, T0, w, b, out, 2, 0);
        hipLaunchKernelGGL(k_spmm_slice, gS, blk, 0, stream, T0, T1, T1,
                           row_ptr, pairs, 2.0f);        // T3 overwrites T1
        hipLaunchKernelGGL(k_accum, gF, blk, 0, stream, T1, w, b, out, 3, 0);
    }
}